// Round 4
// baseline (27949.472 us; speedup 1.0000x reference)
//
#include <hip/hip_runtime.h>
#include <hip/hip_fp16.h>

#define DEV static __device__ __forceinline__

DEV float sigmoidf_(float x) { return 1.f / (1.f + __expf(-x)); }
DEV float tanh_fast(float x) {
    x = fminf(fmaxf(x, -15.f), 15.f);
    float e2 = __expf(2.f * x);
    return (e2 - 1.f) / (e2 + 1.f);
}

// ---- fp16 helpers (fallback message storage only) -------------------------
DEV unsigned short f2h_(float f) {
    __half h = __float2half_rn(f);
    return *reinterpret_cast<unsigned short*>(&h);
}
DEV float h2f_(unsigned short u) {
    __half h = *reinterpret_cast<__half*>(&u);
    return __half2float(h);
}

// ---- 64-element row load/store: fp32 or fp16 storage ----------------------
DEV void loadRow64(const float* __restrict__ p, float v[64]) {
    const float4* q = reinterpret_cast<const float4*>(p);
#pragma unroll
    for (int c = 0; c < 16; c++) {
        float4 x = q[c];
        v[4 * c] = x.x; v[4 * c + 1] = x.y; v[4 * c + 2] = x.z; v[4 * c + 3] = x.w;
    }
}
DEV void loadRow64(const unsigned short* __restrict__ p, float v[64]) {
    const __half2* q = reinterpret_cast<const __half2*>(p);
#pragma unroll
    for (int c = 0; c < 32; c++) {
        float2 f = __half22float2(q[c]);
        v[2 * c] = f.x; v[2 * c + 1] = f.y;
    }
}
DEV void storeRow64(float* __restrict__ p, const float v[64]) {
    float4* q = reinterpret_cast<float4*>(p);
#pragma unroll
    for (int c = 0; c < 16; c++)
        q[c] = make_float4(v[4 * c], v[4 * c + 1], v[4 * c + 2], v[4 * c + 3]);
}
DEV void storeRow64(unsigned short* __restrict__ p, const float v[64]) {
    __half2* q = reinterpret_cast<__half2*>(p);
#pragma unroll
    for (int c = 0; c < 32; c++)
        q[c] = __floats2half2_rn(v[2 * c], v[2 * c + 1]);
}
DEV float loadElem(const float* p) { return *p; }
DEV float loadElem(const unsigned short* p) { return h2f_(*p); }
DEV void storePair(float* row, int c2, float a, float b) {
    reinterpret_cast<float2*>(row)[c2] = make_float2(a, b);
}
DEV void storePair(unsigned short* row, int c2, float a, float b) {
    reinterpret_cast<unsigned*>(row)[c2] =
        (unsigned)f2h_(a) | ((unsigned)f2h_(b) << 16);
}

// ---------------------------------------------------------------------------
// m = relu([message_row, edge_feat(er)] @ W_me + b_me)
// ---------------------------------------------------------------------------
template <typename MsgT>
DEV void edge_m(const MsgT* __restrict__ mrow, float er,
                const float* __restrict__ We, const float* __restrict__ be,
                const float* __restrict__ Wme, const float* __restrict__ bme,
                float m[64]) {
    float x[64];
    loadRow64(mrow, x);
#pragma unroll
    for (int j = 0; j < 64; j++) m[j] = bme[j];
#pragma unroll 1
    for (int k = 0; k < 64; k++) {
        float xk = x[k];
        const float* w = Wme + k * 64;
#pragma unroll
        for (int j = 0; j < 64; j++) m[j] = fmaf(xk, w[j], m[j]);
    }
#pragma unroll 1
    for (int k = 0; k < 64; k++) {
        float ef = fmaxf(fmaf(er, We[k], be[k]), 0.f);
        const float* w = Wme + (64 + k) * 64;
#pragma unroll
        for (int j = 0; j < 64; j++) m[j] = fmaf(ef, w[j], m[j]);
    }
#pragma unroll
    for (int j = 0; j < 64; j++) m[j] = fmaxf(m[j], 0.f);
}

// u = relu((node_agg_row - m) @ W_mp + b_mp)
DEV void mp_mlp(const float* __restrict__ narow, const float m[64],
                const float* __restrict__ Wmp, const float* __restrict__ bmp,
                float u[64]) {
#pragma unroll
    for (int j = 0; j < 64; j++) u[j] = bmp[j];
    const float4* na = reinterpret_cast<const float4*>(narow);
#pragma unroll 1
    for (int c = 0; c < 16; c++) {
        float4 a = na[c];
        float t0 = a.x - m[4 * c + 0], t1 = a.y - m[4 * c + 1];
        float t2 = a.z - m[4 * c + 2], t3 = a.w - m[4 * c + 3];
        const float* w0 = Wmp + (4 * c + 0) * 64;
        const float* w1 = Wmp + (4 * c + 1) * 64;
        const float* w2 = Wmp + (4 * c + 2) * 64;
        const float* w3 = Wmp + (4 * c + 3) * 64;
#pragma unroll
        for (int j = 0; j < 64; j++) {
            float q = u[j];
            q = fmaf(t0, w0[j], q);
            q = fmaf(t1, w1[j], q);
            q = fmaf(t2, w2[j], q);
            q = fmaf(t3, w3[j], q);
            u[j] = q;
        }
    }
#pragma unroll
    for (int j = 0; j < 64; j++) u[j] = fmaxf(u[j], 0.f);
}

// message_row = GRU(u, message_row); scatter into arow
template <typename MsgT>
DEV void gru_update(const float u[64], MsgT* __restrict__ mrow,
                    float* __restrict__ arow,
                    const float* __restrict__ Wih, const float* __restrict__ Whh,
                    const float* __restrict__ bih, const float* __restrict__ bhh) {
    float h[64];
    loadRow64(mrow, h);
#pragma unroll 1
    for (int c2 = 0; c2 < 32; c2++) {
        float out0 = 0.f, out1 = 0.f;
#pragma unroll
        for (int jj = 0; jj < 2; jj++) {
            int j = 2 * c2 + jj;
            const float* wir = Wih + (size_t)j * 64;
            const float* wiz = Wih + (size_t)(64 + j) * 64;
            const float* win = Wih + (size_t)(128 + j) * 64;
            const float* whr = Whh + (size_t)j * 64;
            const float* whz = Whh + (size_t)(64 + j) * 64;
            const float* whn = Whh + (size_t)(128 + j) * 64;
            float gr = bih[j] + bhh[j];
            float gz = bih[64 + j] + bhh[64 + j];
            float gi_n = bih[128 + j];
            float gh_n = bhh[128 + j];
#pragma unroll
            for (int k = 0; k < 64; k++) {
                float uk = u[k], hk = h[k];
                gr = fmaf(uk, wir[k], gr);
                gr = fmaf(hk, whr[k], gr);
                gz = fmaf(uk, wiz[k], gz);
                gz = fmaf(hk, whz[k], gz);
                gi_n = fmaf(uk, win[k], gi_n);
                gh_n = fmaf(hk, whn[k], gh_n);
            }
            float r = sigmoidf_(gr);
            float z = sigmoidf_(gz);
            float n = tanh_fast(gi_n + r * gh_n);
            float hj = loadElem(mrow + j);  // row j not yet overwritten
            float nh = fmaf(z, hj - n, n);  // (1-z)*n + z*h
            if (jj == 0) out0 = nh; else out1 = nh;
            atomicAdd(arow + j, nh);
        }
        storePair(mrow, c2, out0, out1);
    }
}

// ---------------------------------------------------------------------------
// K_init: message = relu([node_feat[src], edge_feat] @ W_init + b_init)
//         scatter message into node_agg2 for nodes_out(layer 0).
// ---------------------------------------------------------------------------
template <typename MsgT>
__global__ __launch_bounds__(256)
void k_init_msg(const int* __restrict__ src, const int* __restrict__ tgt,
                const float* __restrict__ eraw, const float* __restrict__ prob,
                const float* __restrict__ seedp,
                const float* __restrict__ Wn, const float* __restrict__ bn,
                const float* __restrict__ We, const float* __restrict__ be,
                const float* __restrict__ Wi, const float* __restrict__ bi,
                MsgT* __restrict__ message, float* __restrict__ node_agg2, int E) {
    int e = blockIdx.x * blockDim.x + threadIdx.x;
    if (e >= E) return;
    int s = src[e];
    float p = prob[s], sd = seedp[s], er = eraw[e];
    float acc[64];
#pragma unroll
    for (int j = 0; j < 64; j++) acc[j] = bi[j];
#pragma unroll 1
    for (int k = 0; k < 64; k++) {
        float nf = fmaxf(fmaf(p, Wn[k], fmaf(sd, Wn[64 + k], bn[k])), 0.f);
        const float* w = Wi + k * 64;
#pragma unroll
        for (int j = 0; j < 64; j++) acc[j] = fmaf(nf, w[j], acc[j]);
    }
#pragma unroll 1
    for (int k = 0; k < 64; k++) {
        float ef = fmaxf(fmaf(er, We[k], be[k]), 0.f);
        const float* w = Wi + (64 + k) * 64;
#pragma unroll
        for (int j = 0; j < 64; j++) acc[j] = fmaf(ef, w[j], acc[j]);
    }
#pragma unroll
    for (int j = 0; j < 64; j++) acc[j] = fmaxf(acc[j], 0.f);
    storeRow64(message + (size_t)e * 64, acc);
    int t = tgt[e];
    float* arow = node_agg2 + (size_t)t * 64;
#pragma unroll
    for (int j = 0; j < 64; j++) atomicAdd(arow + j, acc[j]);
}

// ---------------------------------------------------------------------------
// K_scatter: m = relu([message,ef] @ W_me + b); scatter-add to node_agg only.
// ---------------------------------------------------------------------------
template <typename MsgT>
__global__ __launch_bounds__(256)
void k_edge_scatter(const int* __restrict__ tgt, const float* __restrict__ eraw,
                    const float* __restrict__ We, const float* __restrict__ be,
                    const float* __restrict__ Wme, const float* __restrict__ bme,
                    const MsgT* __restrict__ message,
                    float* __restrict__ node_agg, int E) {
    int e = blockIdx.x * blockDim.x + threadIdx.x;
    if (e >= E) return;
    float m[64];
    edge_m(message + (size_t)e * 64, eraw[e], We, be, Wme, bme, m);
    int t = tgt[e];
    float* arow = node_agg + (size_t)t * 64;
#pragma unroll
    for (int j = 0; j < 64; j++) atomicAdd(arow + j, m[j]);
}

// ---------------------------------------------------------------------------
// K_gru_pair: thread t owns the mutual reverse pair (t, rev[t]).
//   Recomputes both pair m-values from PRE-update message rows (it is the
//   only writer of those two rows -> race-free in-place update).
// ---------------------------------------------------------------------------
template <typename MsgT>
__global__ __launch_bounds__(256)
void k_gru_pair(const int* __restrict__ src, const int* __restrict__ tgt,
                const int* __restrict__ rev, const float* __restrict__ eraw,
                const float* __restrict__ We, const float* __restrict__ be,
                const float* __restrict__ Wme, const float* __restrict__ bme,
                const float* __restrict__ node_agg,
                const float* __restrict__ Wmp, const float* __restrict__ bmp,
                const float* __restrict__ Wih, const float* __restrict__ Whh,
                const float* __restrict__ bih, const float* __restrict__ bhh,
                MsgT* __restrict__ message, float* __restrict__ node_agg2,
                int half) {
    int t = blockIdx.x * blockDim.x + threadIdx.x;
    if (t >= half) return;
    int rv = rev[t];  // partner edge (mutual: rev[rv] == t)
    int s0 = src[t], s1 = src[rv];
    int g0 = tgt[t], g1 = tgt[rv];

    float mtmp[64], u0[64], u1[64];
    // u0 for edge t: needs m[rev[t]]
    edge_m(message + (size_t)rv * 64, eraw[rv], We, be, Wme, bme, mtmp);
    mp_mlp(node_agg + (size_t)s0 * 64, mtmp, Wmp, bmp, u0);
    // u1 for edge rv: needs m[t]
    edge_m(message + (size_t)t * 64, eraw[t], We, be, Wme, bme, mtmp);
    mp_mlp(node_agg + (size_t)s1 * 64, mtmp, Wmp, bmp, u1);
    // in-place GRU updates of both owned rows
    gru_update(u0, message + (size_t)t * 64, node_agg2 + (size_t)g0 * 64,
               Wih, Whh, bih, bhh);
    gru_update(u1, message + (size_t)rv * 64, node_agg2 + (size_t)g1 * 64,
               Wih, Whh, bih, bhh);
}

// ---------------------------------------------------------------------------
// K_nodes: agg = relu(node_agg2 @ W_aggr + b); logits = relu([agg,nf] @ W_out + b)
//          marg = log_softmax (fp32 out); delta via atomicMax on fp32 bits
// ---------------------------------------------------------------------------
__global__ __launch_bounds__(256)
void k_nodes(const float* __restrict__ node_agg2, const float* __restrict__ prob,
             const float* __restrict__ seedp,
             const float* __restrict__ Wn, const float* __restrict__ bn,
             const float* __restrict__ Wa, const float* __restrict__ ba,
             const float* __restrict__ Wo, const float* __restrict__ bo,
             float* __restrict__ marg, float* __restrict__ prev_p2,
             float* __restrict__ deltas_f, int layer, int N) {
    int n = blockIdx.x * blockDim.x + threadIdx.x;
    if (n >= N) return;
    float a[64];
#pragma unroll
    for (int j = 0; j < 64; j++) a[j] = ba[j];
    const float4* ag = reinterpret_cast<const float4*>(node_agg2 + (size_t)n * 64);
#pragma unroll 1
    for (int c = 0; c < 16; c++) {
        float4 v = ag[c];
        const float* w0 = Wa + (4 * c + 0) * 64;
        const float* w1 = Wa + (4 * c + 1) * 64;
        const float* w2 = Wa + (4 * c + 2) * 64;
        const float* w3 = Wa + (4 * c + 3) * 64;
#pragma unroll
        for (int j = 0; j < 64; j++) {
            float q = a[j];
            q = fmaf(v.x, w0[j], q);
            q = fmaf(v.y, w1[j], q);
            q = fmaf(v.z, w2[j], q);
            q = fmaf(v.w, w3[j], q);
            a[j] = q;
        }
    }
    float l0 = bo[0], l1 = bo[1], l2 = bo[2];
#pragma unroll
    for (int k = 0; k < 64; k++) {
        float ak = fmaxf(a[k], 0.f);
        l0 = fmaf(ak, Wo[k * 3 + 0], l0);
        l1 = fmaf(ak, Wo[k * 3 + 1], l1);
        l2 = fmaf(ak, Wo[k * 3 + 2], l2);
    }
    float p = prob[n], sd = seedp[n];
#pragma unroll 1
    for (int k = 0; k < 64; k++) {
        float nf = fmaxf(fmaf(p, Wn[k], fmaf(sd, Wn[64 + k], bn[k])), 0.f);
        l0 = fmaf(nf, Wo[(64 + k) * 3 + 0], l0);
        l1 = fmaf(nf, Wo[(64 + k) * 3 + 1], l1);
        l2 = fmaf(nf, Wo[(64 + k) * 3 + 2], l2);
    }
    l0 = fmaxf(l0, 0.f); l1 = fmaxf(l1, 0.f); l2 = fmaxf(l2, 0.f);
    float mx = fmaxf(l0, fmaxf(l1, l2));
    float ssum = __expf(l0 - mx) + __expf(l1 - mx) + __expf(l2 - mx);
    float lse = mx + logf(ssum);
    float o0 = l0 - lse, o1 = l1 - lse, o2 = l2 - lse;
    float* out = marg + ((size_t)layer * N + n) * 3;
    out[0] = o0; out[1] = o1; out[2] = o2;
    float p2 = __expf(o2);
    if (layer > 0) {
        float d = fabsf(p2 - prev_p2[n]);
        atomicMax(reinterpret_cast<unsigned int*>(deltas_f + (layer - 1)),
                  __float_as_uint(d));
    }
    prev_p2[n] = p2;
}

__global__ void k_deltas_out(const float* __restrict__ deltas_f,
                             float* __restrict__ out, int L) {
    int i = threadIdx.x;
    if (i < L) out[i] = deltas_f[i];
}

// ---------------------------------------------------------------------------
template <typename MsgT>
static void run_pipeline(void* const* d_in, int E, int N, MsgT* message,
                         float* node_agg, float* node_agg2, float* prev_p2,
                         float* deltas_f, float* marg, float* deltas_out,
                         hipStream_t stream) {
    const int* src = (const int*)d_in[0];
    const int* tgt = (const int*)d_in[1];
    const int* rev = (const int*)d_in[2];
    const float* eraw = (const float*)d_in[3];
    const float* prob = (const float*)d_in[4];
    const float* seedp = (const float*)d_in[5];
    const float* Wn = (const float*)d_in[6];  const float* bn = (const float*)d_in[7];
    const float* We = (const float*)d_in[8];  const float* be = (const float*)d_in[9];
    const float* Wi = (const float*)d_in[10]; const float* bi = (const float*)d_in[11];
    const float* Wa = (const float*)d_in[12]; const float* ba = (const float*)d_in[13];
    const float* Wo = (const float*)d_in[14]; const float* bo = (const float*)d_in[15];
    const float* Wme = (const float*)d_in[16]; const float* bme = (const float*)d_in[17];
    const float* Wmp = (const float*)d_in[18]; const float* bmp = (const float*)d_in[19];
    const float* Wih = (const float*)d_in[20]; const float* Whh = (const float*)d_in[21];
    const float* bih = (const float*)d_in[22]; const float* bhh = (const float*)d_in[23];

    const int L = 4;
    const int half = E / 2;
    dim3 blk(256);
    dim3 eg((E + 255) / 256), pg((half + 255) / 256), ng((N + 255) / 256);

    hipMemsetAsync(deltas_f, 0, L * sizeof(float), stream);
    hipMemsetAsync(node_agg2, 0, (size_t)N * 64 * 4, stream);
    k_init_msg<MsgT><<<eg, blk, 0, stream>>>(src, tgt, eraw, prob, seedp,
                                             Wn, bn, We, be, Wi, bi,
                                             message, node_agg2, E);
    k_nodes<<<ng, blk, 0, stream>>>(node_agg2, prob, seedp, Wn, bn, Wa, ba, Wo, bo,
                                    marg, prev_p2, deltas_f, 0, N);
    for (int l = 0; l < L; l++) {
        hipMemsetAsync(node_agg, 0, (size_t)2 * N * 64 * 4, stream);  // agg + agg2
        k_edge_scatter<MsgT><<<eg, blk, 0, stream>>>(tgt, eraw, We, be, Wme, bme,
                                                     message, node_agg, E);
        k_gru_pair<MsgT><<<pg, blk, 0, stream>>>(src, tgt, rev, eraw,
                                                 We, be, Wme, bme, node_agg,
                                                 Wmp, bmp, Wih, Whh, bih, bhh,
                                                 message, node_agg2, half);
        k_nodes<<<ng, blk, 0, stream>>>(node_agg2, prob, seedp, Wn, bn, Wa, ba,
                                        Wo, bo, marg, prev_p2, deltas_f, l + 1, N);
    }
    k_deltas_out<<<1, 64, 0, stream>>>(deltas_f, deltas_out, L);
}

extern "C" void kernel_launch(void* const* d_in, const int* in_sizes, int n_in,
                              void* d_out, int out_size, void* d_ws, size_t ws_size,
                              hipStream_t stream) {
    const int E = in_sizes[0];
    const int N = in_sizes[4];
    const int L = 4, S = 3;

    float* marg = (float*)d_out;                      // [(L+1),N,S] fp32
    float* deltas_out = marg + (size_t)(L + 1) * N * S;  // [L] fp32

    char* ws = (char*)d_ws;
    float* deltas_f = (float*)ws;                     // 4
    float* prev_p2 = deltas_f + 4;                    // N
    float* node_agg = prev_p2 + N;                    // N*64
    float* node_agg2 = node_agg + (size_t)N * 64;     // N*64 (adjacent for memset)
    char* big = (char*)(node_agg2 + (size_t)N * 64);
    size_t head = (size_t)(big - ws);

    if (ws_size >= head + (size_t)E * 64 * 4) {
        // fp32 message (~230.6 MB total)
        run_pipeline<float>(d_in, E, N, (float*)big, node_agg, node_agg2,
                            prev_p2, deltas_f, marg, deltas_out, stream);
    } else {
        // fp16 message fallback (~128.2 MB total); fp32 compute throughout
        run_pipeline<unsigned short>(d_in, E, N, (unsigned short*)big, node_agg,
                                     node_agg2, prev_p2, deltas_f, marg,
                                     deltas_out, stream);
    }
}

// Round 5
// 8420.624 us; speedup vs baseline: 3.3192x; 3.3192x over previous
//
#include <hip/hip_runtime.h>
#include <hip/hip_fp16.h>

#define DEV static __device__ __forceinline__

DEV float sigmoidf_(float x) { return 1.f / (1.f + __expf(-x)); }
DEV float tanh_fast(float x) {
    x = fminf(fmaxf(x, -15.f), 15.f);
    float e2 = __expf(2.f * x);
    return (e2 - 1.f) / (e2 + 1.f);
}

// ---- fp16 helpers ---------------------------------------------------------
DEV unsigned short f2h_(float f) {
    __half h = __float2half_rn(f);
    return *reinterpret_cast<unsigned short*>(&h);
}
DEV float h2f_(unsigned short u) {
    __half h = *reinterpret_cast<__half*>(&u);
    return __half2float(h);
}

// ---- 64-element row load/store: fp32 or fp16 storage ----------------------
DEV void loadRow64(const float* __restrict__ p, float v[64]) {
    const float4* q = reinterpret_cast<const float4*>(p);
#pragma unroll
    for (int c = 0; c < 16; c++) {
        float4 x = q[c];
        v[4 * c] = x.x; v[4 * c + 1] = x.y; v[4 * c + 2] = x.z; v[4 * c + 3] = x.w;
    }
}
DEV void loadRow64(const unsigned short* __restrict__ p, float v[64]) {
    const uint4* q = reinterpret_cast<const uint4*>(p);  // 8 halves per uint4
#pragma unroll
    for (int c = 0; c < 8; c++) {
        uint4 x = q[c];
        unsigned w[4] = {x.x, x.y, x.z, x.w};
#pragma unroll
        for (int d = 0; d < 4; d++) {
            v[8 * c + 2 * d + 0] = h2f_((unsigned short)(w[d] & 0xffffu));
            v[8 * c + 2 * d + 1] = h2f_((unsigned short)(w[d] >> 16));
        }
    }
}
DEV void storeRow64(float* __restrict__ p, const float v[64]) {
    float4* q = reinterpret_cast<float4*>(p);
#pragma unroll
    for (int c = 0; c < 16; c++)
        q[c] = make_float4(v[4 * c], v[4 * c + 1], v[4 * c + 2], v[4 * c + 3]);
}
DEV void storeRow64(unsigned short* __restrict__ p, const float v[64]) {
    uint4* q = reinterpret_cast<uint4*>(p);
#pragma unroll
    for (int c = 0; c < 8; c++) {
        unsigned w[4];
#pragma unroll
        for (int d = 0; d < 4; d++)
            w[d] = (unsigned)f2h_(v[8 * c + 2 * d]) |
                   ((unsigned)f2h_(v[8 * c + 2 * d + 1]) << 16);
        uint4 x; x.x = w[0]; x.y = w[1]; x.z = w[2]; x.w = w[3];
        q[c] = x;
    }
}
DEV float loadElem(const float* p) { return *p; }
DEV float loadElem(const unsigned short* p) { return h2f_(*p); }
DEV void storePair(float* row, int c2, float a, float b) {
    reinterpret_cast<float2*>(row)[c2] = make_float2(a, b);
}
DEV void storePair(unsigned short* row, int c2, float a, float b) {
    reinterpret_cast<unsigned*>(row)[c2] =
        (unsigned)f2h_(a) | ((unsigned)f2h_(b) << 16);
}

// ---------------------------------------------------------------------------
// CSR build over tgt: deg histogram -> 1-block scan -> fill (int atomics only)
// ---------------------------------------------------------------------------
__global__ void k_deg(const int* __restrict__ tgt, int* __restrict__ deg, int E) {
    int e = blockIdx.x * blockDim.x + threadIdx.x;
    if (e < E) atomicAdd(&deg[tgt[e]], 1);
}

__global__ __launch_bounds__(1024)
void k_scan(const int* __restrict__ deg, int* __restrict__ row_ptr,
            int* __restrict__ cursor, int N) {
    __shared__ int part[1024];
    int tid = threadIdx.x;
    int chunk = (N + 1023) / 1024;
    int lo = tid * chunk, hi = min(lo + chunk, N);
    int s = 0;
    for (int i = lo; i < hi; i++) s += deg[i];
    part[tid] = s;
    __syncthreads();
    for (int off = 1; off < 1024; off <<= 1) {
        int v = (tid >= off) ? part[tid - off] : 0;
        __syncthreads();
        part[tid] += v;
        __syncthreads();
    }
    int base = (tid == 0) ? 0 : part[tid - 1];
    for (int i = lo; i < hi; i++) {
        row_ptr[i] = base;
        cursor[i] = base;
        base += deg[i];
    }
    if (tid == 1023) row_ptr[N] = part[1023];
}

__global__ void k_fill(const int* __restrict__ tgt, int* __restrict__ cursor,
                       int* __restrict__ col_idx, int E) {
    int e = blockIdx.x * blockDim.x + threadIdx.x;
    if (e < E) {
        int pos = atomicAdd(&cursor[tgt[e]], 1);
        col_idx[pos] = e;
    }
}

// ---------------------------------------------------------------------------
// k_agg: wave-per-node coalesced gather-sum of 64-wide rows (no atomics).
//        lane j accumulates feature j over the node's incident edges.
// ---------------------------------------------------------------------------
template <typename T>
__global__ __launch_bounds__(256)
void k_agg(const int* __restrict__ row_ptr, const int* __restrict__ col_idx,
           const T* __restrict__ rows, float* __restrict__ out, int N) {
    int wid = (blockIdx.x * blockDim.x + threadIdx.x) >> 6;
    int lane = threadIdx.x & 63;
    if (wid >= N) return;
    int beg = row_ptr[wid], end = row_ptr[wid + 1];
    float acc = 0.f;
    int i = beg;
    for (; i + 1 < end; i += 2) {
        int e0 = __builtin_amdgcn_readfirstlane(col_idx[i]);
        int e1 = __builtin_amdgcn_readfirstlane(col_idx[i + 1]);
        acc += loadElem(rows + (size_t)e0 * 64 + lane);
        acc += loadElem(rows + (size_t)e1 * 64 + lane);
    }
    if (i < end) {
        int e0 = __builtin_amdgcn_readfirstlane(col_idx[i]);
        acc += loadElem(rows + (size_t)e0 * 64 + lane);
    }
    out[(size_t)wid * 64 + lane] = acc;
}

// ---------------------------------------------------------------------------
// m = relu([message_row, edge_feat(er)] @ W_me + b_me)
// ---------------------------------------------------------------------------
template <typename MsgT>
DEV void edge_m(const MsgT* __restrict__ mrow, float er,
                const float* __restrict__ We, const float* __restrict__ be,
                const float* __restrict__ Wme, const float* __restrict__ bme,
                float m[64]) {
    float x[64];
    loadRow64(mrow, x);
#pragma unroll
    for (int j = 0; j < 64; j++) m[j] = bme[j];
#pragma unroll 1
    for (int k = 0; k < 64; k++) {
        float xk = x[k];
        const float* w = Wme + k * 64;
#pragma unroll
        for (int j = 0; j < 64; j++) m[j] = fmaf(xk, w[j], m[j]);
    }
#pragma unroll 1
    for (int k = 0; k < 64; k++) {
        float ef = fmaxf(fmaf(er, We[k], be[k]), 0.f);
        const float* w = Wme + (64 + k) * 64;
#pragma unroll
        for (int j = 0; j < 64; j++) m[j] = fmaf(ef, w[j], m[j]);
    }
#pragma unroll
    for (int j = 0; j < 64; j++) m[j] = fmaxf(m[j], 0.f);
}

// u = relu((node_agg_row - m) @ W_mp + b_mp)
DEV void mp_mlp(const float* __restrict__ narow, const float m[64],
                const float* __restrict__ Wmp, const float* __restrict__ bmp,
                float u[64]) {
#pragma unroll
    for (int j = 0; j < 64; j++) u[j] = bmp[j];
    const float4* na = reinterpret_cast<const float4*>(narow);
#pragma unroll 1
    for (int c = 0; c < 16; c++) {
        float4 a = na[c];
        float t0 = a.x - m[4 * c + 0], t1 = a.y - m[4 * c + 1];
        float t2 = a.z - m[4 * c + 2], t3 = a.w - m[4 * c + 3];
        const float* w0 = Wmp + (4 * c + 0) * 64;
        const float* w1 = Wmp + (4 * c + 1) * 64;
        const float* w2 = Wmp + (4 * c + 2) * 64;
        const float* w3 = Wmp + (4 * c + 3) * 64;
#pragma unroll
        for (int j = 0; j < 64; j++) {
            float q = u[j];
            q = fmaf(t0, w0[j], q);
            q = fmaf(t1, w1[j], q);
            q = fmaf(t2, w2[j], q);
            q = fmaf(t3, w3[j], q);
            u[j] = q;
        }
    }
#pragma unroll
    for (int j = 0; j < 64; j++) u[j] = fmaxf(u[j], 0.f);
}

// ---------------------------------------------------------------------------
// K_init: message = relu([node_feat[src], edge_feat] @ W_init + b_init)
// ---------------------------------------------------------------------------
template <typename MsgT>
__global__ __launch_bounds__(256)
void k_init_msg(const int* __restrict__ src, const float* __restrict__ eraw,
                const float* __restrict__ prob, const float* __restrict__ seedp,
                const float* __restrict__ Wn, const float* __restrict__ bn,
                const float* __restrict__ We, const float* __restrict__ be,
                const float* __restrict__ Wi, const float* __restrict__ bi,
                MsgT* __restrict__ message, int E) {
    int e = blockIdx.x * blockDim.x + threadIdx.x;
    if (e >= E) return;
    int s = src[e];
    float p = prob[s], sd = seedp[s], er = eraw[e];
    float acc[64];
#pragma unroll
    for (int j = 0; j < 64; j++) acc[j] = bi[j];
#pragma unroll 1
    for (int k = 0; k < 64; k++) {
        float nf = fmaxf(fmaf(p, Wn[k], fmaf(sd, Wn[64 + k], bn[k])), 0.f);
        const float* w = Wi + k * 64;
#pragma unroll
        for (int j = 0; j < 64; j++) acc[j] = fmaf(nf, w[j], acc[j]);
    }
#pragma unroll 1
    for (int k = 0; k < 64; k++) {
        float ef = fmaxf(fmaf(er, We[k], be[k]), 0.f);
        const float* w = Wi + (64 + k) * 64;
#pragma unroll
        for (int j = 0; j < 64; j++) acc[j] = fmaf(ef, w[j], acc[j]);
    }
#pragma unroll
    for (int j = 0; j < 64; j++) acc[j] = fmaxf(acc[j], 0.f);
    storeRow64(message + (size_t)e * 64, acc);
}

// ---------------------------------------------------------------------------
// K_edge_m: m = relu([message,ef] @ W_me + b) -> m_buf (fp16). No atomics.
// ---------------------------------------------------------------------------
template <typename MsgT>
__global__ __launch_bounds__(256)
void k_edge_m(const float* __restrict__ eraw,
              const float* __restrict__ We, const float* __restrict__ be,
              const float* __restrict__ Wme, const float* __restrict__ bme,
              const MsgT* __restrict__ message,
              unsigned short* __restrict__ m_buf, int E) {
    int e = blockIdx.x * blockDim.x + threadIdx.x;
    if (e >= E) return;
    float m[64];
    edge_m(message + (size_t)e * 64, eraw[e], We, be, Wme, bme, m);
    storeRow64(m_buf + (size_t)e * 64, m);
}

// ---------------------------------------------------------------------------
// K_gru: thread-per-edge. m_buf is read-only => in-place message update is
//        race-free. u = relu((node_agg[src]-m_buf[rev])@W_mp+b);
//        message[e] = GRU(u, message[e]). No atomics.
// ---------------------------------------------------------------------------
template <typename MsgT>
__global__ __launch_bounds__(256)
void k_gru(const int* __restrict__ src, const int* __restrict__ rev,
           const float* __restrict__ node_agg,
           const unsigned short* __restrict__ m_buf,
           const float* __restrict__ Wmp, const float* __restrict__ bmp,
           const float* __restrict__ Wih, const float* __restrict__ Whh,
           const float* __restrict__ bih, const float* __restrict__ bhh,
           MsgT* __restrict__ message, int E) {
    int e = blockIdx.x * blockDim.x + threadIdx.x;
    if (e >= E) return;
    int sn = src[e], rv = rev[e];
    float mr[64];
    loadRow64(m_buf + (size_t)rv * 64, mr);
    float u[64];
    mp_mlp(node_agg + (size_t)sn * 64, mr, Wmp, bmp, u);

    MsgT* mrow = message + (size_t)e * 64;
    float h[64];
    loadRow64(mrow, h);
#pragma unroll 1
    for (int c2 = 0; c2 < 32; c2++) {
        float out0 = 0.f, out1 = 0.f;
#pragma unroll
        for (int jj = 0; jj < 2; jj++) {
            int j = 2 * c2 + jj;
            const float* wir = Wih + (size_t)j * 64;
            const float* wiz = Wih + (size_t)(64 + j) * 64;
            const float* win = Wih + (size_t)(128 + j) * 64;
            const float* whr = Whh + (size_t)j * 64;
            const float* whz = Whh + (size_t)(64 + j) * 64;
            const float* whn = Whh + (size_t)(128 + j) * 64;
            float gr = bih[j] + bhh[j];
            float gz = bih[64 + j] + bhh[64 + j];
            float gi_n = bih[128 + j];
            float gh_n = bhh[128 + j];
#pragma unroll
            for (int k = 0; k < 64; k++) {
                float uk = u[k], hk = h[k];
                gr = fmaf(uk, wir[k], gr);
                gr = fmaf(hk, whr[k], gr);
                gz = fmaf(uk, wiz[k], gz);
                gz = fmaf(hk, whz[k], gz);
                gi_n = fmaf(uk, win[k], gi_n);
                gh_n = fmaf(hk, whn[k], gh_n);
            }
            float r = sigmoidf_(gr);
            float z = sigmoidf_(gz);
            float n = tanh_fast(gi_n + r * gh_n);
            float hj = loadElem(mrow + j);  // row j not yet overwritten
            float nh = fmaf(z, hj - n, n);  // (1-z)*n + z*h
            if (jj == 0) out0 = nh; else out1 = nh;
        }
        storePair(mrow, c2, out0, out1);
    }
}

// ---------------------------------------------------------------------------
// K_nodes: agg = relu(node_agg @ W_aggr + b); logits = relu([agg,nf]@W_out+b)
//          marg = log_softmax; delta via atomicMax on fp32 bits
// ---------------------------------------------------------------------------
__global__ __launch_bounds__(256)
void k_nodes(const float* __restrict__ node_agg, const float* __restrict__ prob,
             const float* __restrict__ seedp,
             const float* __restrict__ Wn, const float* __restrict__ bn,
             const float* __restrict__ Wa, const float* __restrict__ ba,
             const float* __restrict__ Wo, const float* __restrict__ bo,
             float* __restrict__ marg, float* __restrict__ prev_p2,
             float* __restrict__ deltas_f, int layer, int N) {
    int n = blockIdx.x * blockDim.x + threadIdx.x;
    if (n >= N) return;
    float a[64];
#pragma unroll
    for (int j = 0; j < 64; j++) a[j] = ba[j];
    const float4* ag = reinterpret_cast<const float4*>(node_agg + (size_t)n * 64);
#pragma unroll 1
    for (int c = 0; c < 16; c++) {
        float4 v = ag[c];
        const float* w0 = Wa + (4 * c + 0) * 64;
        const float* w1 = Wa + (4 * c + 1) * 64;
        const float* w2 = Wa + (4 * c + 2) * 64;
        const float* w3 = Wa + (4 * c + 3) * 64;
#pragma unroll
        for (int j = 0; j < 64; j++) {
            float q = a[j];
            q = fmaf(v.x, w0[j], q);
            q = fmaf(v.y, w1[j], q);
            q = fmaf(v.z, w2[j], q);
            q = fmaf(v.w, w3[j], q);
            a[j] = q;
        }
    }
    float l0 = bo[0], l1 = bo[1], l2 = bo[2];
#pragma unroll
    for (int k = 0; k < 64; k++) {
        float ak = fmaxf(a[k], 0.f);
        l0 = fmaf(ak, Wo[k * 3 + 0], l0);
        l1 = fmaf(ak, Wo[k * 3 + 1], l1);
        l2 = fmaf(ak, Wo[k * 3 + 2], l2);
    }
    float p = prob[n], sd = seedp[n];
#pragma unroll 1
    for (int k = 0; k < 64; k++) {
        float nf = fmaxf(fmaf(p, Wn[k], fmaf(sd, Wn[64 + k], bn[k])), 0.f);
        l0 = fmaf(nf, Wo[(64 + k) * 3 + 0], l0);
        l1 = fmaf(nf, Wo[(64 + k) * 3 + 1], l1);
        l2 = fmaf(nf, Wo[(64 + k) * 3 + 2], l2);
    }
    l0 = fmaxf(l0, 0.f); l1 = fmaxf(l1, 0.f); l2 = fmaxf(l2, 0.f);
    float mx = fmaxf(l0, fmaxf(l1, l2));
    float ssum = __expf(l0 - mx) + __expf(l1 - mx) + __expf(l2 - mx);
    float lse = mx + logf(ssum);
    float o0 = l0 - lse, o1 = l1 - lse, o2 = l2 - lse;
    float* out = marg + ((size_t)layer * N + n) * 3;
    out[0] = o0; out[1] = o1; out[2] = o2;
    float p2 = __expf(o2);
    if (layer > 0) {
        float d = fabsf(p2 - prev_p2[n]);
        atomicMax(reinterpret_cast<unsigned int*>(deltas_f + (layer - 1)),
                  __float_as_uint(d));
    }
    prev_p2[n] = p2;
}

__global__ void k_deltas_out(const float* __restrict__ deltas_f,
                             float* __restrict__ out, int L) {
    int i = threadIdx.x;
    if (i < L) out[i] = deltas_f[i];
}

// ---------------------------------------------------------------------------
template <typename MsgT>
static void run_pipeline(void* const* d_in, int E, int N, MsgT* message,
                         unsigned short* m_buf, float* node_agg,
                         int* deg, int* row_ptr, int* cursor, int* col_idx,
                         float* prev_p2, float* deltas_f, float* marg,
                         float* deltas_out, hipStream_t stream) {
    const int* src = (const int*)d_in[0];
    const int* tgt = (const int*)d_in[1];
    const int* rev = (const int*)d_in[2];
    const float* eraw = (const float*)d_in[3];
    const float* prob = (const float*)d_in[4];
    const float* seedp = (const float*)d_in[5];
    const float* Wn = (const float*)d_in[6];  const float* bn = (const float*)d_in[7];
    const float* We = (const float*)d_in[8];  const float* be = (const float*)d_in[9];
    const float* Wi = (const float*)d_in[10]; const float* bi = (const float*)d_in[11];
    const float* Wa = (const float*)d_in[12]; const float* ba = (const float*)d_in[13];
    const float* Wo = (const float*)d_in[14]; const float* bo = (const float*)d_in[15];
    const float* Wme = (const float*)d_in[16]; const float* bme = (const float*)d_in[17];
    const float* Wmp = (const float*)d_in[18]; const float* bmp = (const float*)d_in[19];
    const float* Wih = (const float*)d_in[20]; const float* Whh = (const float*)d_in[21];
    const float* bih = (const float*)d_in[22]; const float* bhh = (const float*)d_in[23];

    const int L = 4;
    dim3 blk(256);
    dim3 eg((E + 255) / 256), ng((N + 255) / 256);
    dim3 ag((N + 3) / 4);  // wave-per-node, 4 waves/block

    // CSR build (int atomics only)
    hipMemsetAsync(deg, 0, (size_t)N * 4, stream);
    hipMemsetAsync(deltas_f, 0, L * sizeof(float), stream);
    k_deg<<<eg, blk, 0, stream>>>(tgt, deg, E);
    k_scan<<<1, 1024, 0, stream>>>(deg, row_ptr, cursor, N);
    k_fill<<<eg, blk, 0, stream>>>(tgt, cursor, col_idx, E);

    k_init_msg<MsgT><<<eg, blk, 0, stream>>>(src, eraw, prob, seedp,
                                             Wn, bn, We, be, Wi, bi, message, E);
    k_agg<MsgT><<<ag, blk, 0, stream>>>(row_ptr, col_idx, message, node_agg, N);
    k_nodes<<<ng, blk, 0, stream>>>(node_agg, prob, seedp, Wn, bn, Wa, ba, Wo, bo,
                                    marg, prev_p2, deltas_f, 0, N);
    for (int l = 0; l < L; l++) {
        k_edge_m<MsgT><<<eg, blk, 0, stream>>>(eraw, We, be, Wme, bme,
                                               message, m_buf, E);
        k_agg<unsigned short><<<ag, blk, 0, stream>>>(row_ptr, col_idx, m_buf,
                                                      node_agg, N);
        k_gru<MsgT><<<eg, blk, 0, stream>>>(src, rev, node_agg, m_buf,
                                            Wmp, bmp, Wih, Whh, bih, bhh,
                                            message, E);
        k_agg<MsgT><<<ag, blk, 0, stream>>>(row_ptr, col_idx, message,
                                            node_agg, N);
        k_nodes<<<ng, blk, 0, stream>>>(node_agg, prob, seedp, Wn, bn, Wa, ba,
                                        Wo, bo, marg, prev_p2, deltas_f, l + 1, N);
    }
    k_deltas_out<<<1, 64, 0, stream>>>(deltas_f, deltas_out, L);
}

extern "C" void kernel_launch(void* const* d_in, const int* in_sizes, int n_in,
                              void* d_out, int out_size, void* d_ws, size_t ws_size,
                              hipStream_t stream) {
    const int E = in_sizes[0];
    const int N = in_sizes[4];
    const int L = 4, S = 3;

    float* marg = (float*)d_out;                      // [(L+1),N,S] fp32
    float* deltas_out = marg + (size_t)(L + 1) * N * S;  // [L] fp32

    char* ws = (char*)d_ws;
    float* deltas_f = (float*)ws;                     // 4
    float* prev_p2 = deltas_f + 4;                    // N
    int* deg = (int*)(prev_p2 + N);                   // N
    int* row_ptr = deg + N;                           // N+1
    int* cursor = row_ptr + N + 1;                    // N
    int* col_idx = cursor + N;                        // E
    float* node_agg = (float*)(col_idx + E);          // N*64
    char* big = (char*)(node_agg + (size_t)N * 64);
    // 256B-align the big buffers (float4/uint4 access)
    big = (char*)(((uintptr_t)big + 255) & ~(uintptr_t)255);
    size_t head = (size_t)(big - ws);
    size_t msg_f32 = (size_t)E * 64 * 4;
    size_t msg_f16 = (size_t)E * 64 * 2;
    size_t m_f16 = (size_t)E * 64 * 2;

    if (ws_size >= head + msg_f32 + m_f16) {
        // Tier A (~324 MB): fp32 message + fp16 m_buf
        float* message = (float*)big;
        unsigned short* m_buf = (unsigned short*)(big + msg_f32);
        run_pipeline<float>(d_in, E, N, message, m_buf, node_agg,
                            deg, row_ptr, cursor, col_idx,
                            prev_p2, deltas_f, marg, deltas_out, stream);
    } else {
        // Tier B (~222 MB): fp16 message + fp16 m_buf (fp32 compute throughout)
        unsigned short* message = (unsigned short*)big;
        unsigned short* m_buf = (unsigned short*)(big + msg_f16);
        run_pipeline<unsigned short>(d_in, E, N, message, m_buf, node_agg,
                                     deg, row_ptr, cursor, col_idx,
                                     prev_p2, deltas_f, marg, deltas_out, stream);
    }
}

// Round 6
// 8090.392 us; speedup vs baseline: 3.4546x; 1.0408x over previous
//
#include <hip/hip_runtime.h>
#include <hip/hip_fp16.h>

#define DEV static __device__ __forceinline__

DEV float sigmoidf_(float x) { return 1.f / (1.f + __expf(-x)); }
DEV float tanh_fast(float x) {
    x = fminf(fmaxf(x, -15.f), 15.f);
    float e2 = __expf(2.f * x);
    return (e2 - 1.f) / (e2 + 1.f);
}

// ---- fp16 helpers ---------------------------------------------------------
DEV unsigned short f2h_(float f) {
    __half h = __float2half_rn(f);
    return *reinterpret_cast<unsigned short*>(&h);
}
DEV float h2f_(unsigned short u) {
    __half h = *reinterpret_cast<__half*>(&u);
    return __half2float(h);
}

// ---- 8-element chunk loads (compile-time extracts only) -------------------
DEV void load8(const float* __restrict__ p, float x[8]) {
    const float4* q = reinterpret_cast<const float4*>(p);
    float4 a = q[0], b = q[1];
    x[0] = a.x; x[1] = a.y; x[2] = a.z; x[3] = a.w;
    x[4] = b.x; x[5] = b.y; x[6] = b.z; x[7] = b.w;
}
DEV void load8(const unsigned short* __restrict__ p, float x[8]) {
    uint4 v = *reinterpret_cast<const uint4*>(p);
    unsigned w[4] = {v.x, v.y, v.z, v.w};
#pragma unroll
    for (int d = 0; d < 4; d++) {
        x[2 * d + 0] = h2f_((unsigned short)(w[d] & 0xffffu));
        x[2 * d + 1] = h2f_((unsigned short)(w[d] >> 16));
    }
}

// ---- 64-element row load/store (compile-time indices) ---------------------
DEV void loadRow64(const float* __restrict__ p, float v[64]) {
    const float4* q = reinterpret_cast<const float4*>(p);
#pragma unroll
    for (int c = 0; c < 16; c++) {
        float4 x = q[c];
        v[4 * c] = x.x; v[4 * c + 1] = x.y; v[4 * c + 2] = x.z; v[4 * c + 3] = x.w;
    }
}
DEV void loadRow64(const unsigned short* __restrict__ p, float v[64]) {
    const uint4* q = reinterpret_cast<const uint4*>(p);
#pragma unroll
    for (int c = 0; c < 8; c++) {
        uint4 x = q[c];
        unsigned w[4] = {x.x, x.y, x.z, x.w};
#pragma unroll
        for (int d = 0; d < 4; d++) {
            v[8 * c + 2 * d + 0] = h2f_((unsigned short)(w[d] & 0xffffu));
            v[8 * c + 2 * d + 1] = h2f_((unsigned short)(w[d] >> 16));
        }
    }
}
DEV void storeRow64(float* __restrict__ p, const float v[64]) {
    float4* q = reinterpret_cast<float4*>(p);
#pragma unroll
    for (int c = 0; c < 16; c++)
        q[c] = make_float4(v[4 * c], v[4 * c + 1], v[4 * c + 2], v[4 * c + 3]);
}
DEV void storeRow64(unsigned short* __restrict__ p, const float v[64]) {
    uint4* q = reinterpret_cast<uint4*>(p);
#pragma unroll
    for (int c = 0; c < 8; c++) {
        unsigned w[4];
#pragma unroll
        for (int d = 0; d < 4; d++)
            w[d] = (unsigned)f2h_(v[8 * c + 2 * d]) |
                   ((unsigned)f2h_(v[8 * c + 2 * d + 1]) << 16);
        uint4 x; x.x = w[0]; x.y = w[1]; x.z = w[2]; x.w = w[3];
        q[c] = x;
    }
}
DEV float loadElem(const float* p) { return *p; }
DEV float loadElem(const unsigned short* p) { return h2f_(*p); }
DEV void storePair(float* row, int c2, float a, float b) {
    reinterpret_cast<float2*>(row)[c2] = make_float2(a, b);
}
DEV void storePair(unsigned short* row, int c2, float a, float b) {
    reinterpret_cast<unsigned*>(row)[c2] =
        (unsigned)f2h_(a) | ((unsigned)f2h_(b) << 16);
}

// ---------------------------------------------------------------------------
// CSR build over tgt (int atomics only)
// ---------------------------------------------------------------------------
__global__ void k_deg(const int* __restrict__ tgt, int* __restrict__ deg, int E) {
    int e = blockIdx.x * blockDim.x + threadIdx.x;
    if (e < E) atomicAdd(&deg[tgt[e]], 1);
}

__global__ __launch_bounds__(1024)
void k_scan(const int* __restrict__ deg, int* __restrict__ row_ptr,
            int* __restrict__ cursor, int N) {
    __shared__ int part[1024];
    int tid = threadIdx.x;
    int chunk = (N + 1023) / 1024;
    int lo = tid * chunk, hi = min(lo + chunk, N);
    int s = 0;
    for (int i = lo; i < hi; i++) s += deg[i];
    part[tid] = s;
    __syncthreads();
    for (int off = 1; off < 1024; off <<= 1) {
        int v = (tid >= off) ? part[tid - off] : 0;
        __syncthreads();
        part[tid] += v;
        __syncthreads();
    }
    int base = (tid == 0) ? 0 : part[tid - 1];
    for (int i = lo; i < hi; i++) {
        row_ptr[i] = base;
        cursor[i] = base;
        base += deg[i];
    }
    if (tid == 1023) row_ptr[N] = part[1023];
}

__global__ void k_fill(const int* __restrict__ tgt, int* __restrict__ cursor,
                       int* __restrict__ col_idx, int E) {
    int e = blockIdx.x * blockDim.x + threadIdx.x;
    if (e < E) {
        int pos = atomicAdd(&cursor[tgt[e]], 1);
        col_idx[pos] = e;
    }
}

// ---------------------------------------------------------------------------
// k_agg: wave-per-node coalesced gather-sum (lane j = feature j)
// ---------------------------------------------------------------------------
template <typename T>
__global__ __launch_bounds__(256)
void k_agg(const int* __restrict__ row_ptr, const int* __restrict__ col_idx,
           const T* __restrict__ rows, float* __restrict__ out, int N) {
    int wid = (blockIdx.x * blockDim.x + threadIdx.x) >> 6;
    int lane = threadIdx.x & 63;
    if (wid >= N) return;
    int beg = row_ptr[wid], end = row_ptr[wid + 1];
    float acc = 0.f;
    int i = beg;
    for (; i + 1 < end; i += 2) {
        int e0 = __builtin_amdgcn_readfirstlane(col_idx[i]);
        int e1 = __builtin_amdgcn_readfirstlane(col_idx[i + 1]);
        acc += loadElem(rows + (size_t)e0 * 64 + lane);
        acc += loadElem(rows + (size_t)e1 * 64 + lane);
    }
    if (i < end) {
        int e0 = __builtin_amdgcn_readfirstlane(col_idx[i]);
        acc += loadElem(rows + (size_t)e0 * 64 + lane);
    }
    out[(size_t)wid * 64 + lane] = acc;
}

// ---------------------------------------------------------------------------
// m = relu([message_row, edge_feat(er)] @ W_me + b_me)
//   message streamed in chunks of 8 (no dynamically-indexed register array)
// ---------------------------------------------------------------------------
template <typename MsgT>
DEV void edge_m(const MsgT* __restrict__ mrow, float er,
                const float* __restrict__ We, const float* __restrict__ be,
                const float* __restrict__ Wme, const float* __restrict__ bme,
                float m[64]) {
#pragma unroll
    for (int j = 0; j < 64; j++) m[j] = bme[j];
#pragma unroll 1
    for (int c = 0; c < 8; c++) {
        float x[8];
        load8(mrow + 8 * c, x);
#pragma unroll
        for (int i = 0; i < 8; i++) {
            const float* w = Wme + (8 * c + i) * 64;
#pragma unroll
            for (int j = 0; j < 64; j++) m[j] = fmaf(x[i], w[j], m[j]);
        }
    }
#pragma unroll 1
    for (int k = 0; k < 64; k++) {
        float ef = fmaxf(fmaf(er, We[k], be[k]), 0.f);
        const float* w = Wme + (64 + k) * 64;
#pragma unroll
        for (int j = 0; j < 64; j++) m[j] = fmaf(ef, w[j], m[j]);
    }
#pragma unroll
    for (int j = 0; j < 64; j++) m[j] = fmaxf(m[j], 0.f);
}

// u = relu((node_agg_row - m_rev_row) @ W_mp + b_mp), operands streamed 8-wide
DEV void mp_mlp(const float* __restrict__ narow,
                const unsigned short* __restrict__ mrrow,
                const float* __restrict__ Wmp, const float* __restrict__ bmp,
                float u[64]) {
#pragma unroll
    for (int j = 0; j < 64; j++) u[j] = bmp[j];
#pragma unroll 1
    for (int c = 0; c < 8; c++) {
        float a[8], b[8], t[8];
        load8(narow + 8 * c, a);
        load8(mrrow + 8 * c, b);
#pragma unroll
        for (int i = 0; i < 8; i++) t[i] = a[i] - b[i];
#pragma unroll
        for (int i = 0; i < 8; i++) {
            const float* w = Wmp + (8 * c + i) * 64;
#pragma unroll
            for (int j = 0; j < 64; j++) u[j] = fmaf(t[i], w[j], u[j]);
        }
    }
#pragma unroll
    for (int j = 0; j < 64; j++) u[j] = fmaxf(u[j], 0.f);
}

// ---------------------------------------------------------------------------
// K_init: message = relu([node_feat[src], edge_feat] @ W_init + b_init)
// ---------------------------------------------------------------------------
template <typename MsgT>
__global__ __launch_bounds__(256, 2)
void k_init_msg(const int* __restrict__ src, const float* __restrict__ eraw,
                const float* __restrict__ prob, const float* __restrict__ seedp,
                const float* __restrict__ Wn, const float* __restrict__ bn,
                const float* __restrict__ We, const float* __restrict__ be,
                const float* __restrict__ Wi, const float* __restrict__ bi,
                MsgT* __restrict__ message, int E) {
    int e = blockIdx.x * blockDim.x + threadIdx.x;
    if (e >= E) return;
    int s = src[e];
    float p = prob[s], sd = seedp[s], er = eraw[e];
    float acc[64];
#pragma unroll
    for (int j = 0; j < 64; j++) acc[j] = bi[j];
#pragma unroll 1
    for (int k = 0; k < 64; k++) {
        float nf = fmaxf(fmaf(p, Wn[k], fmaf(sd, Wn[64 + k], bn[k])), 0.f);
        const float* w = Wi + k * 64;
#pragma unroll
        for (int j = 0; j < 64; j++) acc[j] = fmaf(nf, w[j], acc[j]);
    }
#pragma unroll 1
    for (int k = 0; k < 64; k++) {
        float ef = fmaxf(fmaf(er, We[k], be[k]), 0.f);
        const float* w = Wi + (64 + k) * 64;
#pragma unroll
        for (int j = 0; j < 64; j++) acc[j] = fmaf(ef, w[j], acc[j]);
    }
#pragma unroll
    for (int j = 0; j < 64; j++) acc[j] = fmaxf(acc[j], 0.f);
    storeRow64(message + (size_t)e * 64, acc);
}

// ---------------------------------------------------------------------------
// K_edge_m: m -> m_buf (fp16). No atomics.
// ---------------------------------------------------------------------------
template <typename MsgT>
__global__ __launch_bounds__(256, 2)
void k_edge_m(const float* __restrict__ eraw,
              const float* __restrict__ We, const float* __restrict__ be,
              const float* __restrict__ Wme, const float* __restrict__ bme,
              const MsgT* __restrict__ message,
              unsigned short* __restrict__ m_buf, int E) {
    int e = blockIdx.x * blockDim.x + threadIdx.x;
    if (e >= E) return;
    float m[64];
    edge_m(message + (size_t)e * 64, eraw[e], We, be, Wme, bme, m);
    storeRow64(m_buf + (size_t)e * 64, m);
}

// ---------------------------------------------------------------------------
// K_gru: thread-per-edge; m_buf read-only => race-free in-place update.
// ---------------------------------------------------------------------------
template <typename MsgT>
__global__ __launch_bounds__(256, 2)
void k_gru(const int* __restrict__ src, const int* __restrict__ rev,
           const float* __restrict__ node_agg,
           const unsigned short* __restrict__ m_buf,
           const float* __restrict__ Wmp, const float* __restrict__ bmp,
           const float* __restrict__ Wih, const float* __restrict__ Whh,
           const float* __restrict__ bih, const float* __restrict__ bhh,
           MsgT* __restrict__ message, int E) {
    int e = blockIdx.x * blockDim.x + threadIdx.x;
    if (e >= E) return;
    int sn = src[e], rv = rev[e];
    float u[64];
    mp_mlp(node_agg + (size_t)sn * 64, m_buf + (size_t)rv * 64, Wmp, bmp, u);

    MsgT* mrow = message + (size_t)e * 64;
    float h[64];
    loadRow64(mrow, h);
#pragma unroll 1
    for (int c2 = 0; c2 < 32; c2++) {
        float out0 = 0.f, out1 = 0.f;
#pragma unroll
        for (int jj = 0; jj < 2; jj++) {
            int j = 2 * c2 + jj;
            const float* wir = Wih + (size_t)j * 64;
            const float* wiz = Wih + (size_t)(64 + j) * 64;
            const float* win = Wih + (size_t)(128 + j) * 64;
            const float* whr = Whh + (size_t)j * 64;
            const float* whz = Whh + (size_t)(64 + j) * 64;
            const float* whn = Whh + (size_t)(128 + j) * 64;
            float gr = bih[j] + bhh[j];
            float gz = bih[64 + j] + bhh[64 + j];
            float gi_n = bih[128 + j];
            float gh_n = bhh[128 + j];
#pragma unroll
            for (int k = 0; k < 64; k++) {
                float uk = u[k], hk = h[k];
                gr = fmaf(uk, wir[k], gr);
                gr = fmaf(hk, whr[k], gr);
                gz = fmaf(uk, wiz[k], gz);
                gz = fmaf(hk, whz[k], gz);
                gi_n = fmaf(uk, win[k], gi_n);
                gh_n = fmaf(hk, whn[k], gh_n);
            }
            float r = sigmoidf_(gr);
            float z = sigmoidf_(gz);
            float n = tanh_fast(gi_n + r * gh_n);
            float hj = loadElem(mrow + j);  // L1 hit; avoids dynamic reg index
            float nh = fmaf(z, hj - n, n);  // (1-z)*n + z*h
            if (jj == 0) out0 = nh; else out1 = nh;
        }
        storePair(mrow, c2, out0, out1);
    }
}

// ---------------------------------------------------------------------------
// K_nodes: agg MLP + out MLP + log_softmax + delta(atomicMax on fp32 bits)
// ---------------------------------------------------------------------------
__global__ __launch_bounds__(256, 2)
void k_nodes(const float* __restrict__ node_agg, const float* __restrict__ prob,
             const float* __restrict__ seedp,
             const float* __restrict__ Wn, const float* __restrict__ bn,
             const float* __restrict__ Wa, const float* __restrict__ ba,
             const float* __restrict__ Wo, const float* __restrict__ bo,
             float* __restrict__ marg, float* __restrict__ prev_p2,
             float* __restrict__ deltas_f, int layer, int N) {
    int n = blockIdx.x * blockDim.x + threadIdx.x;
    if (n >= N) return;
    float a[64];
#pragma unroll
    for (int j = 0; j < 64; j++) a[j] = ba[j];
    const float* ag = node_agg + (size_t)n * 64;
#pragma unroll 1
    for (int c = 0; c < 8; c++) {
        float v[8];
        load8(ag + 8 * c, v);
#pragma unroll
        for (int i = 0; i < 8; i++) {
            const float* w = Wa + (8 * c + i) * 64;
#pragma unroll
            for (int j = 0; j < 64; j++) a[j] = fmaf(v[i], w[j], a[j]);
        }
    }
    float l0 = bo[0], l1 = bo[1], l2 = bo[2];
#pragma unroll
    for (int k = 0; k < 64; k++) {
        float ak = fmaxf(a[k], 0.f);
        l0 = fmaf(ak, Wo[k * 3 + 0], l0);
        l1 = fmaf(ak, Wo[k * 3 + 1], l1);
        l2 = fmaf(ak, Wo[k * 3 + 2], l2);
    }
    float p = prob[n], sd = seedp[n];
#pragma unroll 1
    for (int k = 0; k < 64; k++) {
        float nf = fmaxf(fmaf(p, Wn[k], fmaf(sd, Wn[64 + k], bn[k])), 0.f);
        l0 = fmaf(nf, Wo[(64 + k) * 3 + 0], l0);
        l1 = fmaf(nf, Wo[(64 + k) * 3 + 1], l1);
        l2 = fmaf(nf, Wo[(64 + k) * 3 + 2], l2);
    }
    l0 = fmaxf(l0, 0.f); l1 = fmaxf(l1, 0.f); l2 = fmaxf(l2, 0.f);
    float mx = fmaxf(l0, fmaxf(l1, l2));
    float ssum = __expf(l0 - mx) + __expf(l1 - mx) + __expf(l2 - mx);
    float lse = mx + logf(ssum);
    float o0 = l0 - lse, o1 = l1 - lse, o2 = l2 - lse;
    float* out = marg + ((size_t)layer * N + n) * 3;
    out[0] = o0; out[1] = o1; out[2] = o2;
    float p2 = __expf(o2);
    if (layer > 0) {
        float d = fabsf(p2 - prev_p2[n]);
        atomicMax(reinterpret_cast<unsigned int*>(deltas_f + (layer - 1)),
                  __float_as_uint(d));
    }
    prev_p2[n] = p2;
}

__global__ void k_deltas_out(const float* __restrict__ deltas_f,
                             float* __restrict__ out, int L) {
    int i = threadIdx.x;
    if (i < L) out[i] = deltas_f[i];
}

// ---------------------------------------------------------------------------
template <typename MsgT>
static void run_pipeline(void* const* d_in, int E, int N, MsgT* message,
                         unsigned short* m_buf, float* node_agg,
                         int* deg, int* row_ptr, int* cursor, int* col_idx,
                         float* prev_p2, float* deltas_f, float* marg,
                         float* deltas_out, hipStream_t stream) {
    const int* src = (const int*)d_in[0];
    const int* tgt = (const int*)d_in[1];
    const int* rev = (const int*)d_in[2];
    const float* eraw = (const float*)d_in[3];
    const float* prob = (const float*)d_in[4];
    const float* seedp = (const float*)d_in[5];
    const float* Wn = (const float*)d_in[6];  const float* bn = (const float*)d_in[7];
    const float* We = (const float*)d_in[8];  const float* be = (const float*)d_in[9];
    const float* Wi = (const float*)d_in[10]; const float* bi = (const float*)d_in[11];
    const float* Wa = (const float*)d_in[12]; const float* ba = (const float*)d_in[13];
    const float* Wo = (const float*)d_in[14]; const float* bo = (const float*)d_in[15];
    const float* Wme = (const float*)d_in[16]; const float* bme = (const float*)d_in[17];
    const float* Wmp = (const float*)d_in[18]; const float* bmp = (const float*)d_in[19];
    const float* Wih = (const float*)d_in[20]; const float* Whh = (const float*)d_in[21];
    const float* bih = (const float*)d_in[22]; const float* bhh = (const float*)d_in[23];

    const int L = 4;
    dim3 blk(256);
    dim3 eg((E + 255) / 256), ng((N + 255) / 256);
    dim3 ag((N + 3) / 4);  // wave-per-node, 4 waves/block

    hipMemsetAsync(deg, 0, (size_t)N * 4, stream);
    hipMemsetAsync(deltas_f, 0, L * sizeof(float), stream);
    k_deg<<<eg, blk, 0, stream>>>(tgt, deg, E);
    k_scan<<<1, 1024, 0, stream>>>(deg, row_ptr, cursor, N);
    k_fill<<<eg, blk, 0, stream>>>(tgt, cursor, col_idx, E);

    k_init_msg<MsgT><<<eg, blk, 0, stream>>>(src, eraw, prob, seedp,
                                             Wn, bn, We, be, Wi, bi, message, E);
    k_agg<MsgT><<<ag, blk, 0, stream>>>(row_ptr, col_idx, message, node_agg, N);
    k_nodes<<<ng, blk, 0, stream>>>(node_agg, prob, seedp, Wn, bn, Wa, ba, Wo, bo,
                                    marg, prev_p2, deltas_f, 0, N);
    for (int l = 0; l < L; l++) {
        k_edge_m<MsgT><<<eg, blk, 0, stream>>>(eraw, We, be, Wme, bme,
                                               message, m_buf, E);
        k_agg<unsigned short><<<ag, blk, 0, stream>>>(row_ptr, col_idx, m_buf,
                                                      node_agg, N);
        k_gru<MsgT><<<eg, blk, 0, stream>>>(src, rev, node_agg, m_buf,
                                            Wmp, bmp, Wih, Whh, bih, bhh,
                                            message, E);
        k_agg<MsgT><<<ag, blk, 0, stream>>>(row_ptr, col_idx, message,
                                            node_agg, N);
        k_nodes<<<ng, blk, 0, stream>>>(node_agg, prob, seedp, Wn, bn, Wa, ba,
                                        Wo, bo, marg, prev_p2, deltas_f, l + 1, N);
    }
    k_deltas_out<<<1, 64, 0, stream>>>(deltas_f, deltas_out, L);
}

extern "C" void kernel_launch(void* const* d_in, const int* in_sizes, int n_in,
                              void* d_out, int out_size, void* d_ws, size_t ws_size,
                              hipStream_t stream) {
    const int E = in_sizes[0];
    const int N = in_sizes[4];
    const int L = 4, S = 3;

    float* marg = (float*)d_out;                      // [(L+1),N,S] fp32
    float* deltas_out = marg + (size_t)(L + 1) * N * S;  // [L] fp32

    char* ws = (char*)d_ws;
    float* deltas_f = (float*)ws;                     // 4
    float* prev_p2 = deltas_f + 4;                    // N
    int* deg = (int*)(prev_p2 + N);                   // N
    int* row_ptr = deg + N;                           // N+1
    int* cursor = row_ptr + N + 1;                    // N
    int* col_idx = cursor + N;                        // E
    float* node_agg = (float*)(col_idx + E);          // N*64
    char* big = (char*)(node_agg + (size_t)N * 64);
    big = (char*)(((uintptr_t)big + 255) & ~(uintptr_t)255);
    size_t head = (size_t)(big - ws);
    size_t msg_f32 = (size_t)E * 64 * 4;
    size_t msg_f16 = (size_t)E * 64 * 2;
    size_t m_f16 = (size_t)E * 64 * 2;

    if (ws_size >= head + msg_f32 + m_f16) {
        // Tier A (~324 MB): fp32 message + fp16 m_buf
        float* message = (float*)big;
        unsigned short* m_buf = (unsigned short*)(big + msg_f32);
        run_pipeline<float>(d_in, E, N, message, m_buf, node_agg,
                            deg, row_ptr, cursor, col_idx,
                            prev_p2, deltas_f, marg, deltas_out, stream);
    } else {
        // Tier B (~222 MB): fp16 message + fp16 m_buf (fp32 compute)
        unsigned short* message = (unsigned short*)big;
        unsigned short* m_buf = (unsigned short*)(big + msg_f16);
        run_pipeline<unsigned short>(d_in, E, N, message, m_buf, node_agg,
                                     deg, row_ptr, cursor, col_idx,
                                     prev_p2, deltas_f, marg, deltas_out, stream);
    }
}